// Round 6
// baseline (303.962 us; speedup 1.0000x reference)
//
#include <hip/hip_runtime.h>
#include <math.h>

#define B_  4
#define L_  2048
#define H_  8
#define D_  64
#define U_  40
#define HD  (H_*D_)   // 512

// ---------------------------------------------------------------------------
// Workspace (ws_size confirmed 256 MiB — KC=8 layout always fits):
//   pacc[1280*8*64]@0, pl@2621440, vmean@2662400, M@2670592,
//   mtop@2932736 -> 2,937,856 B
// ---------------------------------------------------------------------------
#define WS_NEED_KC8 2937856

// ---------------------------------------------------------------------------
// threefry2x32 (jax partitionable stream) — verified bit-exact round 4.
// randint(key(42),(2048,40),0,2048) = tf(k2,(0,j)).b1 ^ .b2 & 2047,
// k2 = tf((0,42),(0,1)) constexpr.
// ---------------------------------------------------------------------------
struct U2 { unsigned a, b; };

__host__ __device__ constexpr unsigned rotl32c(unsigned x, int r){
  return (x<<r)|(x>>(32-r));
}

__host__ __device__ constexpr U2 tf2x32(unsigned k0, unsigned k1,
                                        unsigned x0, unsigned x1)
{
  const unsigned k2 = k0 ^ k1 ^ 0x1BD11BDAu;
  const int rA[4] = {13,15,26,6};
  const int rB[4] = {17,29,16,24};
  x0 += k0; x1 += k1;
  for (int i=0;i<4;i++){ x0+=x1; x1=rotl32c(x1,rA[i]); x1^=x0; }
  x0 += k1; x1 += k2 + 1u;
  for (int i=0;i<4;i++){ x0+=x1; x1=rotl32c(x1,rB[i]); x1^=x0; }
  x0 += k2; x1 += k0 + 2u;
  for (int i=0;i<4;i++){ x0+=x1; x1=rotl32c(x1,rA[i]); x1^=x0; }
  x0 += k0; x1 += k1 + 3u;
  for (int i=0;i<4;i++){ x0+=x1; x1=rotl32c(x1,rB[i]); x1^=x0; }
  x0 += k1; x1 += k2 + 4u;
  for (int i=0;i<4;i++){ x0+=x1; x1=rotl32c(x1,rA[i]); x1^=x0; }
  x0 += k2; x1 += k0 + 5u;
  return U2{x0, x1};
}

// ---------------------------------------------------------------------------
// Dispatch 2 kernel: vmean(512 blocks) || M-scores(4096 blocks), fused.
// r5 post-mortem: batching regressed (compiler re-serialized, VGPR 36,
// 45-47 us); occupancy 32->57% did NOT help => per-CU L2 gather path is
// the structural limit (~97 B/cy/CU, at the measured L2 per-CU rate).
// REVERTED to the r4 form (43.2 us): wave = one (b,l,half), 20 samples,
// combined via 256 B LDS; lane = h*8+d8 reads full 2 KB K rows
// contiguously; dot reduced over d8 (xor 1,2,4); b = g&3 -> XCD pair
// owns one 4 MB K[b] slab (L2-resident gather).
// ---------------------------------------------------------------------------
__global__ __launch_bounds__(256) void mvm_kernel(const float* __restrict__ q,
                                                  const float* __restrict__ k,
                                                  const float* __restrict__ v,
                                                  float* __restrict__ M,
                                                  float* __restrict__ vmean)
{
  __shared__ float red[2][2][8][2];   // [l-local][half][h][{max,sum}]
  int tid = threadIdx.x;
  int w = tid >> 6, lane = tid & 63;

  if (blockIdx.x < 512){
    // ---- vmean part: V column sums, atomics into pre-zeroed vmean ----
    int g = blockIdx.x;
    int bh = g & 31, chunk = g >> 5;
    int b = bh >> 3, h = bh & 7;
    int l0 = chunk*128 + w*32;
    float s = 0.f;
    for (int i=0;i<32;i++)
      s += v[(size_t)(b*L_ + l0 + i)*HD + h*D_ + lane];
    atomicAdd(&vmean[bh*D_ + lane], s);
    return;
  }

  // ---- M part: g = lpair*4 + b; wave = (l-local, half) ----
  int g     = blockIdx.x - 512;   // 0..4095
  int b     = g & 3;
  int lpair = g >> 2;             // 0..1023
  int ll    = w >> 1;             // local l 0/1
  int half  = w & 1;              // sample half 0/1
  int l     = lpair*2 + ll;
  int h     = lane >> 3, d8 = lane & 7;

  const float* qrow = q + (size_t)(b*L_ + l)*HD;
  float4 q0 = *(const float4*)(qrow + lane*8);
  float4 q1 = *(const float4*)(qrow + lane*8 + 4);

  constexpr U2 K2 = tf2x32(0u, 42u, 0u, 1u);
  int myidx = 0;
  if (lane < U_){
    U2 r = tf2x32(K2.a, K2.b, 0u, (unsigned)(l*U_ + lane));
    myidx = (int)((r.a ^ r.b) & 2047u);
  }

  const float* kb = k + (size_t)b*L_*HD;
  float vmax = -INFINITY, vsum = 0.f;
  #pragma unroll 10
  for (int s=0;s<20;s++){
    int kidx = __shfl(myidx, half*20 + s, 64);
    const float* kr = kb + (size_t)kidx*HD;
    float4 k0 = *(const float4*)(kr + lane*8);
    float4 k1 = *(const float4*)(kr + lane*8 + 4);
    float p = q0.x*k0.x + q0.y*k0.y + q0.z*k0.z + q0.w*k0.w
            + q1.x*k1.x + q1.y*k1.y + q1.z*k1.z + q1.w*k1.w;
    p += __shfl_xor(p, 1, 64);
    p += __shfl_xor(p, 2, 64);
    p += __shfl_xor(p, 4, 64);    // all 8 lanes of h now hold dot(s)
    vmax = fmaxf(vmax, p);
    vsum += p;
  }
  if (d8 == 0){ red[ll][half][h][0] = vmax; red[ll][half][h][1] = vsum; }
  __syncthreads();
  if (half == 0 && d8 == 0){
    float m2 = red[ll][1][h][0], s2 = red[ll][1][h][1];
    float fm = fmaxf(vmax, m2);
    float fs = vsum + s2;
    M[(b*8 + h)*L_ + l] = fm - fs * (1.0f/(float)L_);
  }
}

// ---------------------------------------------------------------------------
// Dispatch 3 kernel: topk(32 blocks) || init(4096 blocks), fused.
// topk = 4-pass MSB-first 8-bit radix select + atomic compaction (r1:
// replaced 40-iter serial argmax, 43.4 -> ~8 us). Set-equality is what
// matters: indices distinct, scatter rows distinct, tie-count exact.
// ---------------------------------------------------------------------------
__global__ __launch_bounds__(256) void topk_init_kernel(const float* __restrict__ M,
                                                        const float* __restrict__ vmean,
                                                        int*   __restrict__ mtop,
                                                        float* __restrict__ out)
{
  int tid = threadIdx.x;

  if (blockIdx.x >= 32){
    // ---- init part: out[b][l][h][:] = vmean_sum * 1/2048 ----
    int i = (blockIdx.x - 32)*256 + tid;    // float4 index, 0..1048575
    int d4 = i & 15;
    int h  = (i >> 4) & 7;
    int bl = i >> 7;
    int b  = bl >> 11;
    float4 vm = ((const float4*)(vmean + (b*H_ + h)*D_))[d4];
    const float sc = 1.0f/(float)L_;
    float4 o; o.x = vm.x*sc; o.y = vm.y*sc; o.z = vm.z*sc; o.w = vm.w*sc;
    ((float4*)out)[i] = o;
    return;
  }

  // ---- topk part: 4x8-bit MSB-first radix select, then compaction ----
  __shared__ unsigned keys[L_];        // 8 KB: monotone-mapped float keys
  __shared__ unsigned hist[256];
  __shared__ unsigned sh_prefix, sh_need, sh_cgt, sh_ceq;
  int bh = blockIdx.x;

  // load + monotone map (order-preserving float->uint)
  #pragma unroll
  for (int i=0;i<8;i++){
    unsigned bits = __float_as_uint(M[bh*L_ + tid + 256*i]);
    keys[tid + 256*i] = (bits & 0x80000000u) ? ~bits : (bits | 0x80000000u);
  }
  if (tid == 0){ sh_prefix = 0u; sh_need = U_; sh_cgt = 0u; sh_ceq = 0u; }

  unsigned pmask = 0u;                 // bytes already fixed (above pass p)
  for (int p = 3; p >= 0; --p){
    hist[tid] = 0u;
    __syncthreads();                   // hist zeroed; sh_prefix/sh_need valid
    unsigned pref = sh_prefix;
    #pragma unroll
    for (int i=0;i<8;i++){
      unsigned key = keys[tid + 256*i];
      if ((key & pmask) == pref)
        atomicAdd(&hist[(key >> (8*p)) & 255u], 1u);
    }
    __syncthreads();

    if (tid < 64){
      // wave 0: suffix-scan 256 bins (4/lane), pick threshold bucket
      unsigned h0 = hist[tid*4+0], h1 = hist[tid*4+1];
      unsigned h2 = hist[tid*4+2], h3 = hist[tid*4+3];
      unsigned loc = h0+h1+h2+h3;
      unsigned s = loc;
      #pragma unroll
      for (int off=1; off<64; off<<=1){
        unsigned o = __shfl_down(s, off, 64);
        if (tid + off < 64) s += o;
      }                                // s = sum of bins in lanes >= tid
      unsigned need = sh_need;
      unsigned cum = s - loc;          // strictly-higher-lane total
      unsigned bsel = 0xFFFFFFFFu, nn = 0u;
      if (cum < need && cum + h3 >= need){ bsel = tid*4+3; nn = need - cum; }
      cum += h3;
      if (bsel==0xFFFFFFFFu && cum < need && cum + h2 >= need){ bsel = tid*4+2; nn = need - cum; }
      cum += h2;
      if (bsel==0xFFFFFFFFu && cum < need && cum + h1 >= need){ bsel = tid*4+1; nn = need - cum; }
      cum += h1;
      if (bsel==0xFFFFFFFFu && cum < need && cum + h0 >= need){ bsel = tid*4+0; nn = need - cum; }
      if (bsel != 0xFFFFFFFFu){        // exactly one lane qualifies
        sh_prefix = sh_prefix | (bsel << (8*p));
        sh_need = nn;
      }
    }
    __syncthreads();
    pmask |= 0xFFu << (8*p);
  }

  // sh_prefix == exact key of 40th-largest; sh_need == #ties to include
  unsigned K40 = sh_prefix;
  unsigned need = sh_need;
  #pragma unroll
  for (int i=0;i<8;i++){
    int idx = tid + 256*i;
    unsigned key = keys[idx];
    if (key > K40){
      unsigned pos = atomicAdd(&sh_cgt, 1u);       // pos < U_-need
      mtop[bh*U_ + pos] = idx;
    } else if (key == K40){
      unsigned e = atomicAdd(&sh_ceq, 1u);
      if (e < need) mtop[bh*U_ + (U_ - need) + e] = idx;
    }
  }
}

// ---------------------------------------------------------------------------
// Kernel: attention partials. r5 post-mortem: attn has been ~55 us in
// EVERY structure r2-r5 (totals reconciliation) — 2x its ~28 us LDS-pipe
// floor — because stage(VMEM wait) -> barrier -> compute serializes.
// This round: T14 software pipeline. KC=8, nt=2 (128-key tiles), 256 thr
// x 2 qg. Tile t+1's global loads are issued into 64 VGPRs right after
// scores(t); PV(t) (~2700 cy) hides the latency; ds_write lands after
// the post-PV barrier. psQ gets its OWN wave-private region (two 64-key
// PV halves) => psW->PV needs ZERO barriers; 2 barriers/tile total with
// no VMEM stall between them. LDS = Kt[128][68] (verified 0-conflict) +
// Vt[128][64] + Qs[20][64] + psQ[20][64] = 77,824 B -> 2 blocks/CU.
// Qs rows & psQ rows are wave-own (wave w: rows w*5..w*5+4) -> no
// barriers for either. __launch_bounds__(256,2): 256-VGPR budget so the
// 16 staged float4s never spill.
// ---------------------------------------------------------------------------
__global__ __launch_bounds__(256, 2) void attn_kernel(const float* __restrict__ q,
                                                      const float* __restrict__ k,
                                                      const float* __restrict__ v,
                                                      const int*   __restrict__ mtop,
                                                      float* __restrict__ pacc,
                                                      float* __restrict__ pl,
                                                      int nt, int KC)
{
  __shared__ float sh[128*68 + 128*64 + 20*64 + 20*64];   // 77,824 B
  float* Kt  = sh;
  float* Vt  = sh + 128*68;
  float* Qs  = sh + 128*68 + 128*64;
  float* psQ = Qs + 20*64;

  int g  = blockIdx.x;             // 64*KC
  int bh = g & 31, j = g >> 5;
  int kc = j >> 1, qg = j & 1;
  int b = bh >> 3, h = bh & 7;
  int tid = threadIdx.x, w = tid >> 6, lane = tid & 63;

  int srow = (w<<5) + (lane>>4);   // staging: wave w owns rows w*32..+31
  int scol = lane & 15;

  // ---- issue tile-0 K/V global loads into regs ----
  float4 kreg[8], vreg[8];
  {
    int kt0 = (kc*nt)*128;
    const float4* kg = (const float4*)(k + (size_t)(b*L_ + kt0 + srow)*HD + h*D_) + scol;
    const float4* vg = (const float4*)(v + (size_t)(b*L_ + kt0 + srow)*HD + h*D_) + scol;
    #pragma unroll
    for (int i=0;i<8;i++){ kreg[i] = kg[i*512]; vreg[i] = vg[i*512]; }
  }

  // ---- Qs stage: wave-own rows w*5..w*5+4 (no barrier needed) ----
  {
    int r0 = lane >> 4, c = lane & 15;
    int row = w*5 + r0;
    int lstar = mtop[bh*U_ + qg*20 + row];
    ((float4*)(Qs + row*64))[c] =
      ((const float4*)(q + (size_t)(b*L_ + lstar)*HD + h*D_))[c];
    if (lane < 16){
      int row4 = w*5 + 4;
      int l4 = mtop[bh*U_ + qg*20 + row4];
      ((float4*)(Qs + row4*64))[c] =
        ((const float4*)(q + (size_t)(b*L_ + l4)*HD + h*D_))[c];
    }
  }

  // ---- write tile-0 staged regs to LDS ----
  #pragma unroll
  for (int i=0;i<8;i++){
    int row = (w<<5) + (i<<2) + (lane>>4);
    ((float4*)(Kt + row*68))[scol] = kreg[i];
    ((float4*)(Vt + (row<<6)))[scol] = vreg[i];
  }
  __syncthreads();                 // tile 0 staged (Kt/Vt cross-wave)

  float acc[5], lsum[5];
  #pragma unroll
  for (int qq=0;qq<5;qq++){ acc[qq] = 0.f; lsum[qq] = 0.f; }

  for (int tt=0; tt<nt; ++tt){
    // ---- scores: 5 queries x 2 keys (lane, lane+64) ----
    float s0[5], s1[5];
    #pragma unroll
    for (int qq=0;qq<5;qq++){ s0[qq] = 0.f; s1[qq] = 0.f; }
    const float* kr0 = Kt + lane*68;
    const float* kr1 = Kt + (lane+64)*68;
    #pragma unroll
    for (int t=0;t<16;t++){
      float4 k0 = ((const float4*)kr0)[t];
      float4 k1 = ((const float4*)kr1)[t];
      #pragma unroll
      for (int qq=0;qq<5;qq++){
        float4 qf = ((const float4*)(Qs + (w*5+qq)*64))[t];
        s0[qq] += k0.x*qf.x + k0.y*qf.y + k0.z*qf.z + k0.w*qf.w;
        s1[qq] += k1.x*qf.x + k1.y*qf.y + k1.z*qf.z + k1.w*qf.w;
      }
    }

    // ---- issue NEXT tile's global loads (hidden under PV below) ----
    if (tt+1 < nt){
      int kt1 = (kc*nt + tt + 1)*128;
      const float4* kg = (const float4*)(k + (size_t)(b*L_ + kt1 + srow)*HD + h*D_) + scol;
      const float4* vg = (const float4*)(v + (size_t)(b*L_ + kt1 + srow)*HD + h*D_) + scol;
      #pragma unroll
      for (int i=0;i<8;i++){ kreg[i] = kg[i*512]; vreg[i] = vg[i*512]; }
    }

    // ---- softmax-partial + PV, two 64-key halves; psQ rows wave-own
    //      => no barriers in this whole phase ----
    #pragma unroll
    for (int half=0; half<2; ++half){
      #pragma unroll
      for (int qq=0;qq<5;qq++){
        float p = __expf((half ? s1[qq] : s0[qq])*0.125f);
        psQ[(w*5+qq)*64 + lane] = p;
        lsum[qq] += p;
      }
      #pragma unroll 4
      for (int k4=0;k4<16;k4++){
        int rb = half*64 + k4*4;
        float v0 = Vt[(rb+0)*64 + lane];
        float v1 = Vt[(rb+1)*64 + lane];
        float v2 = Vt[(rb+2)*64 + lane];
        float v3 = Vt[(rb+3)*64 + lane];
        #pragma unroll
        for (int qq=0;qq<5;qq++){
          float4 pp = ((const float4*)(psQ + (w*5+qq)*64))[k4];
          acc[qq] += pp.x*v0 + pp.y*v1 + pp.z*v2 + pp.w*v3;
        }
      }
    }

    __syncthreads();               // all waves done reading Kt/Vt

    if (tt+1 < nt){
      // ---- write staged regs (compiler inserts the vmcnt wait here) ----
      #pragma unroll
      for (int i=0;i<8;i++){
        int row = (w<<5) + (i<<2) + (lane>>4);
        ((float4*)(Kt + row*68))[scol] = kreg[i];
        ((float4*)(Vt + (row<<6)))[scol] = vreg[i];
      }
      __syncthreads();             // next tile staged
    }
  }

  // epilogue: exclusive (gu,kc) partial slice — no atomics
  #pragma unroll
  for (int qq=0;qq<5;qq++){
    float ls = lsum[qq];
    #pragma unroll
    for (int off=32; off; off>>=1) ls += __shfl_xor(ls, off, 64);
    int gu = bh*U_ + qg*20 + w*5 + qq;
    pacc[(size_t)(gu*KC + kc)*64 + lane] = acc[qq];
    if (lane == 0) pl[gu*KC + kc] = ls;
  }
}

// ---------------------------------------------------------------------------
// Kernel: sum KC partials per (bh,u), normalize, scatter selected rows.
// ---------------------------------------------------------------------------
__global__ __launch_bounds__(256) void combine_kernel(const int* __restrict__ mtop,
                                                      const float* __restrict__ pacc,
                                                      const float* __restrict__ pl,
                                                      float* __restrict__ out,
                                                      int KC)
{
  int gu = blockIdx.x*4 + (threadIdx.x >> 6);  // 0..1279
  int lane = threadIdx.x & 63;
  int bh = gu / U_, u = gu - bh*U_;
  float a = 0.f, L = 0.f;
  for (int c=0;c<KC;c++){
    a += pacc[(size_t)(gu*KC + c)*64 + lane];
    L += pl[gu*KC + c];
  }
  int b = bh >> 3, h = bh & 7;
  int lstar = mtop[bh*U_ + u];
  out[(size_t)(b*L_ + lstar)*HD + h*D_ + lane] = a / L;
}

// ---------------------------------------------------------------------------
extern "C" void kernel_launch(void* const* d_in, const int* in_sizes, int n_in,
                              void* d_out, int out_size, void* d_ws, size_t ws_size,
                              hipStream_t stream)
{
  const float* q = (const float*)d_in[0];
  const float* k = (const float*)d_in[1];
  const float* v = (const float*)d_in[2];
  float* out = (float*)d_out;

  int KC = (ws_size >= (size_t)WS_NEED_KC8) ? 8 : 4;
  int nt = 16 / KC;

  size_t o_pl    = (size_t)1280*KC*64*4;
  size_t o_vmean = o_pl + (size_t)1280*KC*4;
  size_t o_M     = o_vmean + 2048*4;
  size_t o_mtop  = o_M + 65536*4;

  float* pacc  = (float*)d_ws;
  float* pl    = (float*)((char*)d_ws + o_pl);
  float* vmean = (float*)((char*)d_ws + o_vmean);
  float* M     = (float*)((char*)d_ws + o_M);
  int*   mtop  = (int*)  ((char*)d_ws + o_mtop);

  hipMemsetAsync(vmean, 0, 2048*sizeof(float), stream);
  mvm_kernel      <<<4608,  256, 0, stream>>>(q, k, v, M, vmean);
  topk_init_kernel<<<4128,  256, 0, stream>>>(M, vmean, mtop, out);
  attn_kernel     <<<64*KC, 256, 0, stream>>>(q, k, v, mtop, pacc, pl, nt, KC);
  combine_kernel  <<<320,   256, 0, stream>>>(mtop, pacc, pl, out, KC);
}

// Round 7
// 172.427 us; speedup vs baseline: 1.7629x; 1.7629x over previous
//
#include <hip/hip_runtime.h>
#include <math.h>

#define B_  4
#define L_  2048
#define H_  8
#define D_  64
#define U_  40
#define HD  (H_*D_)   // 512

// ---------------------------------------------------------------------------
// Workspace (ws_size confirmed 256 MiB — KC=8 layout always fits):
//   pacc[1280*8*64]@0, pl@2621440, vmean@2662400, M@2670592,
//   mtop@2932736 -> 2,937,856 B
// ---------------------------------------------------------------------------
#define WS_NEED_KC8 2937856

// ---------------------------------------------------------------------------
// threefry2x32 (jax partitionable stream) — verified bit-exact round 4.
// randint(key(42),(2048,40),0,2048) = tf(k2,(0,j)).b1 ^ .b2 & 2047,
// k2 = tf((0,42),(0,1)) constexpr.
// ---------------------------------------------------------------------------
struct U2 { unsigned a, b; };

__host__ __device__ constexpr unsigned rotl32c(unsigned x, int r){
  return (x<<r)|(x>>(32-r));
}

__host__ __device__ constexpr U2 tf2x32(unsigned k0, unsigned k1,
                                        unsigned x0, unsigned x1)
{
  const unsigned k2 = k0 ^ k1 ^ 0x1BD11BDAu;
  const int rA[4] = {13,15,26,6};
  const int rB[4] = {17,29,16,24};
  x0 += k0; x1 += k1;
  for (int i=0;i<4;i++){ x0+=x1; x1=rotl32c(x1,rA[i]); x1^=x0; }
  x0 += k1; x1 += k2 + 1u;
  for (int i=0;i<4;i++){ x0+=x1; x1=rotl32c(x1,rB[i]); x1^=x0; }
  x0 += k2; x1 += k0 + 2u;
  for (int i=0;i<4;i++){ x0+=x1; x1=rotl32c(x1,rA[i]); x1^=x0; }
  x0 += k0; x1 += k1 + 3u;
  for (int i=0;i<4;i++){ x0+=x1; x1=rotl32c(x1,rB[i]); x1^=x0; }
  x0 += k1; x1 += k2 + 4u;
  for (int i=0;i<4;i++){ x0+=x1; x1=rotl32c(x1,rA[i]); x1^=x0; }
  x0 += k2; x1 += k0 + 5u;
  return U2{x0, x1};
}

// ---------------------------------------------------------------------------
// Dispatch 1 kernel: vmean(32 blocks, no atomics/memset) || M-scores
// (2048 blocks), fused. Session ledger r2-r6: mvm stuck at 42-47 us
// across FOUR structures (monolithic, 2-wave split, reg-batched, occ
// 32->57%) — the 671 MB L2 row-gather at ~17 TB/s aggregate is the
// structural ceiling; this is the proven r0/r1 monolithic form (~42 us).
// vmean NEW this round: one block per bh, 4 waves x 512 rows each,
// LDS-reduced, direct store — removes the hipMemsetAsync dispatch and
// the atomics. m part: wave = one (b,l), all 8 h; lane = h*8+d8 reads
// full 2 KB K rows contiguously; dot reduced over d8 (xor 1,2,4);
// b = g&3 (grid offset 32 preserves the mod-8/XCD alignment) -> each
// XCD owns one K[b] slab (L2-resident gather).
// ---------------------------------------------------------------------------
__global__ __launch_bounds__(256) void mvm_kernel(const float* __restrict__ q,
                                                  const float* __restrict__ k,
                                                  const float* __restrict__ v,
                                                  float* __restrict__ M,
                                                  float* __restrict__ vmean)
{
  int tid = threadIdx.x;
  int w = tid >> 6, lane = tid & 63;

  if (blockIdx.x < 32){
    // ---- vmean part: block = one bh; waves sum 512 rows each ----
    __shared__ float red[4][64];
    int bh = blockIdx.x;
    int b = bh >> 3, h = bh & 7;
    const float* vb = v + (size_t)b*L_*HD + h*D_ + lane;
    int l0 = w*512;
    float s = 0.f;
    for (int i=0;i<512;i++)
      s += vb[(size_t)(l0 + i)*HD];
    red[w][lane] = s;
    __syncthreads();
    if (w == 0)
      vmean[bh*D_ + lane] = red[0][lane]+red[1][lane]+red[2][lane]+red[3][lane];
    return;
  }

  // ---- M part ----
  int g    = blockIdx.x - 32;     // 0..2047, g = lblk*4 + b
  int b    = g & 3;
  int lblk = g >> 2;
  int l    = lblk*4 + w;
  int h    = lane >> 3, d8 = lane & 7;

  const float* qrow = q + (size_t)(b*L_ + l)*HD;
  float4 q0 = *(const float4*)(qrow + lane*8);
  float4 q1 = *(const float4*)(qrow + lane*8 + 4);

  constexpr U2 K2 = tf2x32(0u, 42u, 0u, 1u);
  int myidx = 0;
  if (lane < U_){
    U2 r = tf2x32(K2.a, K2.b, 0u, (unsigned)(l*U_ + lane));
    myidx = (int)((r.a ^ r.b) & 2047u);
  }

  const float* kb = k + (size_t)b*L_*HD;
  float vmax = -INFINITY, vsum = 0.f;
  #pragma unroll 8
  for (int s=0;s<U_;s++){
    int kidx = __shfl(myidx, s, 64);
    const float* kr = kb + (size_t)kidx*HD;
    float4 k0 = *(const float4*)(kr + lane*8);
    float4 k1 = *(const float4*)(kr + lane*8 + 4);
    float p = q0.x*k0.x + q0.y*k0.y + q0.z*k0.z + q0.w*k0.w
            + q1.x*k1.x + q1.y*k1.y + q1.z*k1.z + q1.w*k1.w;
    p += __shfl_xor(p, 1, 64);
    p += __shfl_xor(p, 2, 64);
    p += __shfl_xor(p, 4, 64);    // all 8 lanes of h now hold dot(s)
    vmax = fmaxf(vmax, p);
    vsum += p;
  }
  if (d8 == 0)
    M[(b*8 + h)*L_ + l] = vmax - vsum * (1.0f/(float)L_);
}

// ---------------------------------------------------------------------------
// Dispatch 2 kernel: topk(32 blocks) || init(4096 blocks), fused.
// topk = 4-pass MSB-first 8-bit radix select + atomic compaction (r1:
// replaced 40-iter serial argmax, 43.4 -> ~8 us). Set-equality is what
// matters: indices distinct, scatter rows distinct, tie-count exact.
// ---------------------------------------------------------------------------
__global__ __launch_bounds__(256) void topk_init_kernel(const float* __restrict__ M,
                                                        const float* __restrict__ vmean,
                                                        int*   __restrict__ mtop,
                                                        float* __restrict__ out)
{
  int tid = threadIdx.x;

  if (blockIdx.x >= 32){
    // ---- init part: out[b][l][h][:] = vmean_sum * 1/2048 ----
    int i = (blockIdx.x - 32)*256 + tid;    // float4 index, 0..1048575
    int d4 = i & 15;
    int h  = (i >> 4) & 7;
    int bl = i >> 7;
    int b  = bl >> 11;
    float4 vm = ((const float4*)(vmean + (b*H_ + h)*D_))[d4];
    const float sc = 1.0f/(float)L_;
    float4 o; o.x = vm.x*sc; o.y = vm.y*sc; o.z = vm.z*sc; o.w = vm.w*sc;
    ((float4*)out)[i] = o;
    return;
  }

  // ---- topk part: 4x8-bit MSB-first radix select, then compaction ----
  __shared__ unsigned keys[L_];        // 8 KB: monotone-mapped float keys
  __shared__ unsigned hist[256];
  __shared__ unsigned sh_prefix, sh_need, sh_cgt, sh_ceq;
  int bh = blockIdx.x;

  // load + monotone map (order-preserving float->uint)
  #pragma unroll
  for (int i=0;i<8;i++){
    unsigned bits = __float_as_uint(M[bh*L_ + tid + 256*i]);
    keys[tid + 256*i] = (bits & 0x80000000u) ? ~bits : (bits | 0x80000000u);
  }
  if (tid == 0){ sh_prefix = 0u; sh_need = U_; sh_cgt = 0u; sh_ceq = 0u; }

  unsigned pmask = 0u;                 // bytes already fixed (above pass p)
  for (int p = 3; p >= 0; --p){
    hist[tid] = 0u;
    __syncthreads();                   // hist zeroed; sh_prefix/sh_need valid
    unsigned pref = sh_prefix;
    #pragma unroll
    for (int i=0;i<8;i++){
      unsigned key = keys[tid + 256*i];
      if ((key & pmask) == pref)
        atomicAdd(&hist[(key >> (8*p)) & 255u], 1u);
    }
    __syncthreads();

    if (tid < 64){
      // wave 0: suffix-scan 256 bins (4/lane), pick threshold bucket
      unsigned h0 = hist[tid*4+0], h1 = hist[tid*4+1];
      unsigned h2 = hist[tid*4+2], h3 = hist[tid*4+3];
      unsigned loc = h0+h1+h2+h3;
      unsigned s = loc;
      #pragma unroll
      for (int off=1; off<64; off<<=1){
        unsigned o = __shfl_down(s, off, 64);
        if (tid + off < 64) s += o;
      }                                // s = sum of bins in lanes >= tid
      unsigned need = sh_need;
      unsigned cum = s - loc;          // strictly-higher-lane total
      unsigned bsel = 0xFFFFFFFFu, nn = 0u;
      if (cum < need && cum + h3 >= need){ bsel = tid*4+3; nn = need - cum; }
      cum += h3;
      if (bsel==0xFFFFFFFFu && cum < need && cum + h2 >= need){ bsel = tid*4+2; nn = need - cum; }
      cum += h2;
      if (bsel==0xFFFFFFFFu && cum < need && cum + h1 >= need){ bsel = tid*4+1; nn = need - cum; }
      cum += h1;
      if (bsel==0xFFFFFFFFu && cum < need && cum + h0 >= need){ bsel = tid*4+0; nn = need - cum; }
      if (bsel != 0xFFFFFFFFu){        // exactly one lane qualifies
        sh_prefix = sh_prefix | (bsel << (8*p));
        sh_need = nn;
      }
    }
    __syncthreads();
    pmask |= 0xFFu << (8*p);
  }

  // sh_prefix == exact key of 40th-largest; sh_need == #ties to include
  unsigned K40 = sh_prefix;
  unsigned need = sh_need;
  #pragma unroll
  for (int i=0;i<8;i++){
    int idx = tid + 256*i;
    unsigned key = keys[idx];
    if (key > K40){
      unsigned pos = atomicAdd(&sh_cgt, 1u);       // pos < U_-need
      mtop[bh*U_ + pos] = idx;
    } else if (key == K40){
      unsigned e = atomicAdd(&sh_ceq, 1u);
      if (e < need) mtop[bh*U_ + (U_ - need) + e] = idx;
    }
  }
}

// ---------------------------------------------------------------------------
// Kernel: attention partials. REVERTED to the proven r1 structure (best
// total 157 us; attn ~42) with ONE delta: psQ moved out of the Kt
// overlay into its own wave-private [20][64] region, PV processed in two
// 64-key halves. psQ write->read is same-wave (lgkmcnt-ordered), so the
// two overlay barriers disappear: 2 barriers/tile instead of 4. NO reg
// prefetch (r6 spilled: 64 staged VGPRs across a barrier -> scratch,
// 243 MB fetch). LDS = Kt[128][68] (pad-68, 0 conflicts) + Vt[128][64] +
// Qs[20][64] + psQ[20][64] = 77,824 B -> 2 blocks/CU, 8 waves/CU.
// KC=8, nt=2, grid = 32 bh x KC x 2 qg = 512; bh = g&31 -> per-XCD
// K+V working set 4 MB = L2. __launch_bounds__(256,3) = proven
// anti-spill (VGPR 84 in r0/r1).
// ---------------------------------------------------------------------------
__global__ __launch_bounds__(256, 3) void attn_kernel(const float* __restrict__ q,
                                                      const float* __restrict__ k,
                                                      const float* __restrict__ v,
                                                      const int*   __restrict__ mtop,
                                                      float* __restrict__ pacc,
                                                      float* __restrict__ pl,
                                                      int nt, int KC)
{
  __shared__ float sh[128*68 + 128*64 + 20*64 + 20*64];   // 77,824 B
  float* Kt  = sh;
  float* Vt  = sh + 128*68;
  float* Qs  = sh + 128*68 + 128*64;
  float* psQ = Qs + 20*64;

  int g  = blockIdx.x;             // 64*KC
  int bh = g & 31, j = g >> 5;
  int kc = j >> 1, qg = j & 1;
  int b = bh >> 3, h = bh & 7;
  int tid = threadIdx.x, w = tid >> 6, lane = tid & 63;

  // stage Qs: 20 rows x 16 float4 = 320 float4
  #pragma unroll
  for (int c=0;c<2;c++){
    int flat = c*256 + tid;
    if (flat < 320){
      int row = flat >> 4, col = flat & 15;
      int lstar = mtop[bh*U_ + qg*20 + row];
      ((float4*)(Qs + row*64))[col] =
        ((const float4*)(q + (size_t)(b*L_ + lstar)*HD + h*D_))[col];
    }
  }

  float acc[5], lsum[5];
  #pragma unroll
  for (int qq=0;qq<5;qq++){ acc[qq] = 0.f; lsum[qq] = 0.f; }

  for (int tt=0; tt<nt; ++tt){     // runtime trip count pins code shape
    int kt = (kc*nt + tt)*128;
    if (tt) __syncthreads();       // prior tile's Kt/Vt reads done
    #pragma unroll
    for (int c=0;c<8;c++){
      int flat = c*256 + tid;
      int row = flat >> 4, col = flat & 15;
      ((float4*)(Kt + row*68))[col] =
        ((const float4*)(k + (size_t)(b*L_ + kt + row)*HD + h*D_))[col];
      ((float4*)(Vt + row*64))[col] =
        ((const float4*)(v + (size_t)(b*L_ + kt + row)*HD + h*D_))[col];
    }
    __syncthreads();               // Qs + Kt + Vt staged

    // scores: 5 queries x 2 keys per lane
    float s0[5], s1[5];
    #pragma unroll
    for (int qq=0;qq<5;qq++){ s0[qq] = 0.f; s1[qq] = 0.f; }
    const float* kr0 = Kt + lane*68;
    const float* kr1 = Kt + (lane+64)*68;
    #pragma unroll
    for (int t=0;t<16;t++){
      float4 k0 = ((const float4*)kr0)[t];
      float4 k1 = ((const float4*)kr1)[t];
      #pragma unroll
      for (int qq=0;qq<5;qq++){
        float4 qf = ((const float4*)(Qs + (w*5+qq)*64))[t];
        s0[qq] += k0.x*qf.x + k0.y*qf.y + k0.z*qf.z + k0.w*qf.w;
        s1[qq] += k1.x*qf.x + k1.y*qf.y + k1.z*qf.z + k1.w*qf.w;
      }
    }

    // softmax-partial + PV, two 64-key halves; psQ rows wave-own =>
    // no barriers in this phase (same-wave ds write->read ordering)
    #pragma unroll
    for (int half=0; half<2; ++half){
      #pragma unroll
      for (int qq=0;qq<5;qq++){
        float p = __expf((half ? s1[qq] : s0[qq])*0.125f);
        psQ[(w*5+qq)*64 + lane] = p;
        lsum[qq] += p;
      }
      #pragma unroll 4
      for (int k4=0;k4<16;k4++){
        int rb = half*64 + k4*4;
        float v0 = Vt[(rb+0)*64 + lane];
        float v1 = Vt[(rb+1)*64 + lane];
        float v2 = Vt[(rb+2)*64 + lane];
        float v3 = Vt[(rb+3)*64 + lane];
        #pragma unroll
        for (int qq=0;qq<5;qq++){
          float4 pp = ((const float4*)(psQ + (w*5+qq)*64))[k4];
          acc[qq] += pp.x*v0 + pp.y*v1 + pp.z*v2 + pp.w*v3;
        }
      }
    }
  }

  // epilogue: exclusive (gu,kc) partial slice — no atomics
  #pragma unroll
  for (int qq=0;qq<5;qq++){
    float ls = lsum[qq];
    #pragma unroll
    for (int off=32; off; off>>=1) ls += __shfl_xor(ls, off, 64);
    int gu = bh*U_ + qg*20 + w*5 + qq;
    pacc[(size_t)(gu*KC + kc)*64 + lane] = acc[qq];
    if (lane == 0) pl[gu*KC + kc] = ls;
  }
}

// ---------------------------------------------------------------------------
// Kernel: sum KC partials per (bh,u), normalize, scatter selected rows.
// ---------------------------------------------------------------------------
__global__ __launch_bounds__(256) void combine_kernel(const int* __restrict__ mtop,
                                                      const float* __restrict__ pacc,
                                                      const float* __restrict__ pl,
                                                      float* __restrict__ out,
                                                      int KC)
{
  int gu = blockIdx.x*4 + (threadIdx.x >> 6);  // 0..1279
  int lane = threadIdx.x & 63;
  int bh = gu / U_, u = gu - bh*U_;
  float a = 0.f, L = 0.f;
  for (int c=0;c<KC;c++){
    a += pacc[(size_t)(gu*KC + c)*64 + lane];
    L += pl[gu*KC + c];
  }
  int b = bh >> 3, h = bh & 7;
  int lstar = mtop[bh*U_ + u];
  out[(size_t)(b*L_ + lstar)*HD + h*D_ + lane] = a / L;
}

// ---------------------------------------------------------------------------
extern "C" void kernel_launch(void* const* d_in, const int* in_sizes, int n_in,
                              void* d_out, int out_size, void* d_ws, size_t ws_size,
                              hipStream_t stream)
{
  const float* q = (const float*)d_in[0];
  const float* k = (const float*)d_in[1];
  const float* v = (const float*)d_in[2];
  float* out = (float*)d_out;

  int KC = (ws_size >= (size_t)WS_NEED_KC8) ? 8 : 4;
  int nt = 16 / KC;

  size_t o_pl    = (size_t)1280*KC*64*4;
  size_t o_vmean = o_pl + (size_t)1280*KC*4;
  size_t o_M     = o_vmean + 2048*4;
  size_t o_mtop  = o_M + 65536*4;

  float* pacc  = (float*)d_ws;
  float* pl    = (float*)((char*)d_ws + o_pl);
  float* vmean = (float*)((char*)d_ws + o_vmean);
  float* M     = (float*)((char*)d_ws + o_M);
  int*   mtop  = (int*)  ((char*)d_ws + o_mtop);

  mvm_kernel      <<<2080,  256, 0, stream>>>(q, k, v, M, vmean);
  topk_init_kernel<<<4128,  256, 0, stream>>>(M, vmean, mtop, out);
  attn_kernel     <<<64*KC, 256, 0, stream>>>(q, k, v, mtop, pacc, pl, nt, KC);
  combine_kernel  <<<320,   256, 0, stream>>>(mtop, pacc, pl, out, KC);
}

// Round 8
// 156.413 us; speedup vs baseline: 1.9433x; 1.1024x over previous
//
#include <hip/hip_runtime.h>
#include <math.h>

#define B_  4
#define L_  2048
#define H_  8
#define D_  64
#define U_  40
#define HD  (H_*D_)   // 512

// ---------------------------------------------------------------------------
// Workspace (ws_size confirmed 256 MiB — KC=8 layout always fits):
//   pacc[1280*8*64]@0, pl@2621440, vmean@2662400, M@2670592,
//   mtop@2932736 -> 2,937,856 B
// ---------------------------------------------------------------------------
#define WS_NEED_KC8 2937856

// ---------------------------------------------------------------------------
// threefry2x32 (jax partitionable stream) — verified bit-exact round 4.
// randint(key(42),(2048,40),0,2048) = tf(k2,(0,j)).b1 ^ .b2 & 2047,
// k2 = tf((0,42),(0,1)) constexpr.
// ---------------------------------------------------------------------------
struct U2 { unsigned a, b; };

__host__ __device__ constexpr unsigned rotl32c(unsigned x, int r){
  return (x<<r)|(x>>(32-r));
}

__host__ __device__ constexpr U2 tf2x32(unsigned k0, unsigned k1,
                                        unsigned x0, unsigned x1)
{
  const unsigned k2 = k0 ^ k1 ^ 0x1BD11BDAu;
  const int rA[4] = {13,15,26,6};
  const int rB[4] = {17,29,16,24};
  x0 += k0; x1 += k1;
  for (int i=0;i<4;i++){ x0+=x1; x1=rotl32c(x1,rA[i]); x1^=x0; }
  x0 += k1; x1 += k2 + 1u;
  for (int i=0;i<4;i++){ x0+=x1; x1=rotl32c(x1,rB[i]); x1^=x0; }
  x0 += k2; x1 += k0 + 2u;
  for (int i=0;i<4;i++){ x0+=x1; x1=rotl32c(x1,rA[i]); x1^=x0; }
  x0 += k0; x1 += k1 + 3u;
  for (int i=0;i<4;i++){ x0+=x1; x1=rotl32c(x1,rB[i]); x1^=x0; }
  x0 += k1; x1 += k2 + 4u;
  for (int i=0;i<4;i++){ x0+=x1; x1=rotl32c(x1,rA[i]); x1^=x0; }
  x0 += k2; x1 += k0 + 5u;
  return U2{x0, x1};
}

// ---------------------------------------------------------------------------
// Dispatch 2 kernel: vmean(512 blocks) || M-scores(2048 blocks), fused.
// EXACT r1 form (best total 157.0; mvm ~42-43). r7's 32-block vmean
// fusion regressed (straggler: 512 serial strided loads/block) — reverted.
// Session ledger r2-r7: m-part stuck at 42-47 us across FOUR structures
// (monolithic, 2-wave split, reg-batched, occ 32->57%) — the 655 MB L2
// row-gather is the structural ceiling. Do not touch again.
// m part: wave = one (b,l), all 8 h; lane = h*8+d8 reads full 2 KB K
// rows contiguously; dot reduced over d8 (xor 1,2,4); b = g&3.
// ---------------------------------------------------------------------------
__global__ __launch_bounds__(256) void mvm_kernel(const float* __restrict__ q,
                                                  const float* __restrict__ k,
                                                  const float* __restrict__ v,
                                                  float* __restrict__ M,
                                                  float* __restrict__ vmean)
{
  int tid = threadIdx.x;
  int w = tid >> 6, lane = tid & 63;

  if (blockIdx.x < 512){
    // ---- vmean part: V column sums, atomics into pre-zeroed vmean ----
    int g = blockIdx.x;
    int bh = g & 31, chunk = g >> 5;
    int b = bh >> 3, h = bh & 7;
    int l0 = chunk*128 + w*32;
    float s = 0.f;
    for (int i=0;i<32;i++)
      s += v[(size_t)(b*L_ + l0 + i)*HD + h*D_ + lane];
    atomicAdd(&vmean[bh*D_ + lane], s);
    return;
  }

  // ---- M part ----
  int g    = blockIdx.x - 512;    // 0..2047, g = lblk*4 + b
  int b    = g & 3;
  int lblk = g >> 2;
  int l    = lblk*4 + w;
  int h    = lane >> 3, d8 = lane & 7;

  const float* qrow = q + (size_t)(b*L_ + l)*HD;
  float4 q0 = *(const float4*)(qrow + lane*8);
  float4 q1 = *(const float4*)(qrow + lane*8 + 4);

  constexpr U2 K2 = tf2x32(0u, 42u, 0u, 1u);
  int myidx = 0;
  if (lane < U_){
    U2 r = tf2x32(K2.a, K2.b, 0u, (unsigned)(l*U_ + lane));
    myidx = (int)((r.a ^ r.b) & 2047u);
  }

  const float* kb = k + (size_t)b*L_*HD;
  float vmax = -INFINITY, vsum = 0.f;
  #pragma unroll 8
  for (int s=0;s<U_;s++){
    int kidx = __shfl(myidx, s, 64);
    const float* kr = kb + (size_t)kidx*HD;
    float4 k0 = *(const float4*)(kr + lane*8);
    float4 k1 = *(const float4*)(kr + lane*8 + 4);
    float p = q0.x*k0.x + q0.y*k0.y + q0.z*k0.z + q0.w*k0.w
            + q1.x*k1.x + q1.y*k1.y + q1.z*k1.z + q1.w*k1.w;
    p += __shfl_xor(p, 1, 64);
    p += __shfl_xor(p, 2, 64);
    p += __shfl_xor(p, 4, 64);    // all 8 lanes of h now hold dot(s)
    vmax = fmaxf(vmax, p);
    vsum += p;
  }
  if (d8 == 0)
    M[(b*8 + h)*L_ + l] = vmax - vsum * (1.0f/(float)L_);
}

// ---------------------------------------------------------------------------
// Dispatch 3 kernel: topk(32 blocks) || init(4096 blocks), fused.
// topk = 4-pass MSB-first 8-bit radix select + atomic compaction (r1:
// replaced 40-iter serial argmax, 43.4 -> ~8 us). Set-equality is what
// matters: indices distinct, scatter rows distinct, tie-count exact.
// ---------------------------------------------------------------------------
__global__ __launch_bounds__(256) void topk_init_kernel(const float* __restrict__ M,
                                                        const float* __restrict__ vmean,
                                                        int*   __restrict__ mtop,
                                                        float* __restrict__ out)
{
  int tid = threadIdx.x;

  if (blockIdx.x >= 32){
    // ---- init part: out[b][l][h][:] = vmean_sum * 1/2048 ----
    int i = (blockIdx.x - 32)*256 + tid;    // float4 index, 0..1048575
    int d4 = i & 15;
    int h  = (i >> 4) & 7;
    int bl = i >> 7;
    int b  = bl >> 11;
    float4 vm = ((const float4*)(vmean + (b*H_ + h)*D_))[d4];
    const float sc = 1.0f/(float)L_;
    float4 o; o.x = vm.x*sc; o.y = vm.y*sc; o.z = vm.z*sc; o.w = vm.w*sc;
    ((float4*)out)[i] = o;
    return;
  }

  // ---- topk part: 4x8-bit MSB-first radix select, then compaction ----
  __shared__ unsigned keys[L_];        // 8 KB: monotone-mapped float keys
  __shared__ unsigned hist[256];
  __shared__ unsigned sh_prefix, sh_need, sh_cgt, sh_ceq;
  int bh = blockIdx.x;

  // load + monotone map (order-preserving float->uint)
  #pragma unroll
  for (int i=0;i<8;i++){
    unsigned bits = __float_as_uint(M[bh*L_ + tid + 256*i]);
    keys[tid + 256*i] = (bits & 0x80000000u) ? ~bits : (bits | 0x80000000u);
  }
  if (tid == 0){ sh_prefix = 0u; sh_need = U_; sh_cgt = 0u; sh_ceq = 0u; }

  unsigned pmask = 0u;                 // bytes already fixed (above pass p)
  for (int p = 3; p >= 0; --p){
    hist[tid] = 0u;
    __syncthreads();                   // hist zeroed; sh_prefix/sh_need valid
    unsigned pref = sh_prefix;
    #pragma unroll
    for (int i=0;i<8;i++){
      unsigned key = keys[tid + 256*i];
      if ((key & pmask) == pref)
        atomicAdd(&hist[(key >> (8*p)) & 255u], 1u);
    }
    __syncthreads();

    if (tid < 64){
      // wave 0: suffix-scan 256 bins (4/lane), pick threshold bucket
      unsigned h0 = hist[tid*4+0], h1 = hist[tid*4+1];
      unsigned h2 = hist[tid*4+2], h3 = hist[tid*4+3];
      unsigned loc = h0+h1+h2+h3;
      unsigned s = loc;
      #pragma unroll
      for (int off=1; off<64; off<<=1){
        unsigned o = __shfl_down(s, off, 64);
        if (tid + off < 64) s += o;
      }                                // s = sum of bins in lanes >= tid
      unsigned need = sh_need;
      unsigned cum = s - loc;          // strictly-higher-lane total
      unsigned bsel = 0xFFFFFFFFu, nn = 0u;
      if (cum < need && cum + h3 >= need){ bsel = tid*4+3; nn = need - cum; }
      cum += h3;
      if (bsel==0xFFFFFFFFu && cum < need && cum + h2 >= need){ bsel = tid*4+2; nn = need - cum; }
      cum += h2;
      if (bsel==0xFFFFFFFFu && cum < need && cum + h1 >= need){ bsel = tid*4+1; nn = need - cum; }
      cum += h1;
      if (bsel==0xFFFFFFFFu && cum < need && cum + h0 >= need){ bsel = tid*4+0; nn = need - cum; }
      if (bsel != 0xFFFFFFFFu){        // exactly one lane qualifies
        sh_prefix = sh_prefix | (bsel << (8*p));
        sh_need = nn;
      }
    }
    __syncthreads();
    pmask |= 0xFFu << (8*p);
  }

  // sh_prefix == exact key of 40th-largest; sh_need == #ties to include
  unsigned K40 = sh_prefix;
  unsigned need = sh_need;
  #pragma unroll
  for (int i=0;i<8;i++){
    int idx = tid + 256*i;
    unsigned key = keys[idx];
    if (key > K40){
      unsigned pos = atomicAdd(&sh_cgt, 1u);       // pos < U_-need
      mtop[bh*U_ + pos] = idx;
    } else if (key == K40){
      unsigned e = atomicAdd(&sh_ceq, 1u);
      if (e < need) mtop[bh*U_ + (U_ - need) + e] = idx;
    }
  }
}

// ---------------------------------------------------------------------------
// Kernel: attention partials. EXACT r1 structure (best total 157.0,
// attn ~42; 6 rewrites r2-r7 all failed to beat it) with ONE new line:
// tile-order STAGGER by block pairing parity. Mechanism: exactly 2
// identical blocks/CU run in lockstep (same launch, same phase lengths)
// -> both stage (VMEM burst+drain) simultaneously, exposing the stage
// latency every tile instead of hiding it under the partner's compute.
// Dispatch round-robins XCDs then CUs, so blocks g and g+256 co-reside;
// parity (g>>8)&1 reverses one partner's tile order -> A computes tile 0
// while B stages tile 1, and vice versa. Pure fp-sum reorder otherwise.
// Kt pad-68 (0 conflicts), Vt in LDS, psQ overlays Kt after scores.
// KC=8, nt=2; bh = g&31 -> per-XCD K+V working set 4 MB = L2.
// __launch_bounds__(256,3) = proven anti-spill (VGPR 84).
// ---------------------------------------------------------------------------
__global__ __launch_bounds__(256, 3) void attn_kernel(const float* __restrict__ q,
                                                      const float* __restrict__ k,
                                                      const float* __restrict__ v,
                                                      const int*   __restrict__ mtop,
                                                      float* __restrict__ pacc,
                                                      float* __restrict__ pl,
                                                      int nt, int KC)
{
  __shared__ float sh[128*68 + 128*64 + 20*64];  // Kt + Vt + Qs = 72,704 B
  float* Kt  = sh;                 // psQ[20][128] overlays after scores
  float* Vt  = sh + 128*68;
  float* Qs  = sh + 128*68 + 128*64;
  float* psQ = sh;

  int g  = blockIdx.x;             // 64*KC
  int bh = g & 31, j = g >> 5;
  int kc = j >> 1, qg = j & 1;
  int b = bh >> 3, h = bh & 7;
  int tid = threadIdx.x, w = tid >> 6, lane = tid & 63;
  int par = (g >> 8) & 1;          // co-resident pair parity (g, g+256)

  // stage Qs: 20 rows x 16 float4 = 320 float4
  #pragma unroll
  for (int c=0;c<2;c++){
    int flat = c*256 + tid;
    if (flat < 320){
      int row = flat >> 4, col = flat & 15;
      int lstar = mtop[bh*U_ + qg*20 + row];
      ((float4*)(Qs + row*64))[col] =
        ((const float4*)(q + (size_t)(b*L_ + lstar)*HD + h*D_))[col];
    }
  }

  float acc[5], lsum[5];
  #pragma unroll
  for (int qq=0;qq<5;qq++){ acc[qq] = 0.f; lsum[qq] = 0.f; }

  for (int tt=0; tt<nt; ++tt){     // runtime trip count pins code shape
    int tta = par ? (nt-1-tt) : tt;          // STAGGER: parity-reversed order
    int kt = (kc*nt + tta)*128;
    __syncthreads();               // Qs ready / prior tile's psQ+Vt reads done
    #pragma unroll
    for (int c=0;c<8;c++){
      int flat = c*256 + tid;
      int row = flat >> 4, col = flat & 15;
      ((float4*)(Kt + row*68))[col] =
        ((const float4*)(k + (size_t)(b*L_ + kt + row)*HD + h*D_))[col];
      ((float4*)(Vt + row*64))[col] =
        ((const float4*)(v + (size_t)(b*L_ + kt + row)*HD + h*D_))[col];
    }
    __syncthreads();

    // scores: 5 queries x 2 keys per lane
    float s0[5], s1[5];
    #pragma unroll
    for (int qq=0;qq<5;qq++){ s0[qq] = 0.f; s1[qq] = 0.f; }
    const float* kr0 = Kt + lane*68;
    const float* kr1 = Kt + (lane+64)*68;
    #pragma unroll
    for (int t=0;t<16;t++){
      float4 k0 = ((const float4*)kr0)[t];
      float4 k1 = ((const float4*)kr1)[t];
      #pragma unroll
      for (int qq=0;qq<5;qq++){
        float4 qf = ((const float4*)(Qs + (w*5+qq)*64))[t];
        s0[qq] += k0.x*qf.x + k0.y*qf.y + k0.z*qf.z + k0.w*qf.w;
        s1[qq] += k1.x*qf.x + k1.y*qf.y + k1.z*qf.z + k1.w*qf.w;
      }
    }
    __syncthreads();   // Kt reads done before psQ overlay

    #pragma unroll
    for (int qq=0;qq<5;qq++){
      float p0 = __expf(s0[qq]*0.125f);
      float p1 = __expf(s1[qq]*0.125f);
      psQ[(w*5+qq)*128 + lane]      = p0;
      psQ[(w*5+qq)*128 + lane + 64] = p1;
      lsum[qq] += p0 + p1;         // per-lane; reduced once in epilogue
    }
    __syncthreads();   // psQ visible before PV / next restage

    // PV: lane = output dim; wave's 5 queries, all 128 keys from Vt
    for (int k4=0;k4<32;k4++){
      float v0 = Vt[(4*k4+0)*64 + lane];
      float v1 = Vt[(4*k4+1)*64 + lane];
      float v2 = Vt[(4*k4+2)*64 + lane];
      float v3 = Vt[(4*k4+3)*64 + lane];
      #pragma unroll
      for (int qq=0;qq<5;qq++){
        float4 pp = ((const float4*)(psQ + (w*5+qq)*128))[k4];
        acc[qq] += pp.x*v0 + pp.y*v1 + pp.z*v2 + pp.w*v3;
      }
    }
  }

  // epilogue: exclusive (gu,kc) partial slice — no atomics
  #pragma unroll
  for (int qq=0;qq<5;qq++){
    float ls = lsum[qq];
    #pragma unroll
    for (int off=32; off; off>>=1) ls += __shfl_xor(ls, off, 64);
    int gu = bh*U_ + qg*20 + w*5 + qq;
    pacc[(size_t)(gu*KC + kc)*64 + lane] = acc[qq];
    if (lane == 0) pl[gu*KC + kc] = ls;
  }
}

// ---------------------------------------------------------------------------
// Kernel: sum KC partials per (bh,u), normalize, scatter selected rows.
// ---------------------------------------------------------------------------
__global__ __launch_bounds__(256) void combine_kernel(const int* __restrict__ mtop,
                                                      const float* __restrict__ pacc,
                                                      const float* __restrict__ pl,
                                                      float* __restrict__ out,
                                                      int KC)
{
  int gu = blockIdx.x*4 + (threadIdx.x >> 6);  // 0..1279
  int lane = threadIdx.x & 63;
  int bh = gu / U_, u = gu - bh*U_;
  float a = 0.f, L = 0.f;
  for (int c=0;c<KC;c++){
    a += pacc[(size_t)(gu*KC + c)*64 + lane];
    L += pl[gu*KC + c];
  }
  int b = bh >> 3, h = bh & 7;
  int lstar = mtop[bh*U_ + u];
  out[(size_t)(b*L_ + lstar)*HD + h*D_ + lane] = a / L;
}

// ---------------------------------------------------------------------------
extern "C" void kernel_launch(void* const* d_in, const int* in_sizes, int n_in,
                              void* d_out, int out_size, void* d_ws, size_t ws_size,
                              hipStream_t stream)
{
  const float* q = (const float*)d_in[0];
  const float* k = (const float*)d_in[1];
  const float* v = (const float*)d_in[2];
  float* out = (float*)d_out;

  int KC = (ws_size >= (size_t)WS_NEED_KC8) ? 8 : 4;
  int nt = 16 / KC;

  size_t o_pl    = (size_t)1280*KC*64*4;
  size_t o_vmean = o_pl + (size_t)1280*KC*4;
  size_t o_M     = o_vmean + 2048*4;
  size_t o_mtop  = o_M + 65536*4;

  float* pacc  = (float*)d_ws;
  float* pl    = (float*)((char*)d_ws + o_pl);
  float* vmean = (float*)((char*)d_ws + o_vmean);
  float* M     = (float*)((char*)d_ws + o_M);
  int*   mtop  = (int*)  ((char*)d_ws + o_mtop);

  hipMemsetAsync(vmean, 0, 2048*sizeof(float), stream);
  mvm_kernel      <<<2560,  256, 0, stream>>>(q, k, v, M, vmean);
  topk_init_kernel<<<4128,  256, 0, stream>>>(M, vmean, mtop, out);
  attn_kernel     <<<64*KC, 256, 0, stream>>>(q, k, v, mtop, pacc, pl, nt, KC);
  combine_kernel  <<<320,   256, 0, stream>>>(mtop, pacc, pl, out, KC);
}